// Round 2
// 701.144 us; speedup vs baseline: 1.0258x; 1.0258x over previous
//
#include <hip/hip_runtime.h>

#define LEAKY 0.2f

// Problem constants (from reference setup_inputs)
constexpr int H = 2, B = 2048, M = 32, Dd = 32;
constexpr int NSLOT = H * B * M;          // 131072

// True clang vector type — required by __builtin_nontemporal_{load,store}
// (HIP's float4 is a class and is rejected by the builtin).
typedef float f32x4 __attribute__((ext_vector_type(4)));

// ---------------------------------------------------------------------------
// Kernel 1: passthrough copies uEmbed -> out[0], iEmbed -> out[1]
// Pure streaming, no reuse: non-temporal both ways so we don't evict the
// relation/entity tables from L2 before gather_kernel runs.
// ---------------------------------------------------------------------------
__global__ void copy_ui_kernel(const f32x4* __restrict__ u,
                               const f32x4* __restrict__ it,
                               f32x4* __restrict__ out_u,
                               f32x4* __restrict__ out_i, int n4) {
    int i = blockIdx.x * blockDim.x + threadIdx.x;
    if (i < n4) {
        f32x4 uv = __builtin_nontemporal_load(&u[i]);
        f32x4 iv = __builtin_nontemporal_load(&it[i]);
        __builtin_nontemporal_store(uv, &out_u[i]);
        __builtin_nontemporal_store(iv, &out_i[i]);
    }
}

// ---------------------------------------------------------------------------
// Kernel 2: winner[pos_items[b]] = max b  (numpy last-occurrence-wins scatter)
// winner must be pre-initialized to -1 (memset 0xFF)
// ---------------------------------------------------------------------------
__global__ void winner_kernel(const int* __restrict__ pos,
                              int* __restrict__ winner, int n) {
    int i = blockIdx.x * blockDim.x + threadIdx.x;
    if (i < n) atomicMax(&winner[pos[i]], i);
}

// ---------------------------------------------------------------------------
// Kernel 3: one wave (64 lanes) per slot s in [0, H*B*M):
//   - copy relation_emb[r_idx] (1024 f32) -> r_all[s]      (the 537 MB stream)
//   - gather entity_emb[h_idx] -> h_all[s]
//   - gather leaky_relu(entity_emb[t_idx]) -> t_all[s]
//   - fused Rh[s][d] = sum_e R[d][e] * h[e]  -> ws  (item-independent!)
// float4 j = lane + 64k covers floats 4j..4j+3; d = j/8 = lane/8 + 8k,
// e = (4j)%32 = (4*lane)%32 (k-independent -> one h float4 load per lane).
//
// Cache policy is the point of this version:
//   - out_r stores are NON-TEMPORAL: 537 MB of streaming stores must not
//     evict the 800 KB relation table from per-XCD L2 (that eviction was
//     forcing every relation read back to HBM ~ doubling gather traffic).
//   - entity loads are NON-TEMPORAL: 64 MB table, ~zero reuse (131k draws
//     over 500k rows) -> don't pollute L2 with them.
//   - Rh / out_t stores stay CACHED: ripple_kernel re-reads exactly these
//     33 MB immediately afterwards and should hit L2.
// ---------------------------------------------------------------------------
__global__ __launch_bounds__(256) void gather_kernel(
    const int* __restrict__ mh, const int* __restrict__ mr,
    const int* __restrict__ mt, const float* __restrict__ ent,
    const float* __restrict__ rel, float* __restrict__ out_h,
    float* __restrict__ out_t, float* __restrict__ out_r,
    float* __restrict__ Rh) {
    int tid  = blockIdx.x * blockDim.x + threadIdx.x;
    int s    = tid >> 6;           // slot (one wave per slot)
    int lane = threadIdx.x & 63;
    if (s >= NSLOT) return;

    int hidx = mh[s], ridx = mr[s], tidx = mt[s];

    const f32x4* src = (const f32x4*)(rel + (size_t)ridx * (Dd * Dd));
    f32x4*       dst = (f32x4*)(out_r + (size_t)s * (Dd * Dd));

    // h fragment this lane needs: e0 = (4*lane) & 31
    int e0 = (lane * 4) & 31;
    f32x4 hv = __builtin_nontemporal_load(
        (const f32x4*)(ent + (size_t)hidx * Dd + e0));

    float partial[4];
#pragma unroll
    for (int k = 0; k < 4; k++) {
        f32x4 v = src[lane + 64 * k];            // cached: rel stays in L2
        __builtin_nontemporal_store(v, &dst[lane + 64 * k]);
        partial[k] = v.x * hv.x + v.y * hv.y + v.z * hv.z + v.w * hv.w;
    }
    // reduce across the 8 lanes sharing a d-row
#pragma unroll
    for (int off = 1; off < 8; off <<= 1) {
#pragma unroll
        for (int k = 0; k < 4; k++)
            partial[k] += __shfl_xor(partial[k], off, 64);
    }
    if ((lane & 7) == 0) {
        int dbase = lane >> 3;
#pragma unroll
        for (int k = 0; k < 4; k++)
            Rh[(size_t)s * Dd + dbase + 8 * k] = partial[k];   // cached
    }
    if (lane < 8) {
        // hv for lanes 0..7 is exactly h[4*lane .. 4*lane+3]
        __builtin_nontemporal_store(hv, &((f32x4*)(out_h + (size_t)s * Dd))[lane]);
        f32x4 tv = __builtin_nontemporal_load(
            (const f32x4*)(ent + (size_t)tidx * Dd + lane * 4));
        tv.x = tv.x > 0.f ? tv.x : LEAKY * tv.x;
        tv.y = tv.y > 0.f ? tv.y : LEAKY * tv.y;
        tv.z = tv.z > 0.f ? tv.z : LEAKY * tv.z;
        tv.w = tv.w > 0.f ? tv.w : LEAKY * tv.w;
        ((f32x4*)(out_t + (size_t)s * Dd))[lane] = tv;         // cached
    }
}

// ---------------------------------------------------------------------------
// Kernel 4: per-b ripple hops (one wave per b).
// lanes 0..31 own m (or d/e) = lane&31; upper half duplicates for 2-way split
// of the 32-length dot products (half = lane>>5 handles e in [16h,16h+16)).
// ---------------------------------------------------------------------------
__global__ __launch_bounds__(64) void ripple_kernel(
    const int* __restrict__ pos_items, const float* __restrict__ iEmbed,
    const float* __restrict__ W, const float* __restrict__ Rh,
    const float* __restrict__ t_all, const int* __restrict__ winner,
    float* __restrict__ out_i) {
    int b = blockIdx.x;
    int lane = threadIdx.x;
    int m = lane & 31, half = lane >> 5;

    __shared__ float item[32], pv[32], pre[32];

    int pos = pos_items[b];
    if (lane < 32) item[lane] = iEmbed[(size_t)pos * Dd + lane];
    __syncthreads();

    for (int hop = 0; hop < H; hop++) {
        const float* Rhb = Rh    + (size_t)(hop * B + b) * M * Dd;
        const float* tb  = t_all + (size_t)(hop * B + b) * M * Dd;

        // logits[m] = dot(Rh[m,:], item)
        float partial = 0.f;
        for (int e = half * 16; e < half * 16 + 16; e++)
            partial += Rhb[m * Dd + e] * item[e];
        partial += __shfl_xor(partial, 32, 64);

        // softmax over 32 m (both halves hold identical copies; xor masks
        // 16..1 stay within each half)
        float mx = partial;
#pragma unroll
        for (int msk = 16; msk >= 1; msk >>= 1)
            mx = fmaxf(mx, __shfl_xor(mx, msk, 64));
        float ex = __expf(partial - mx);
        float sm = ex;
#pragma unroll
        for (int msk = 16; msk >= 1; msk >>= 1)
            sm += __shfl_xor(sm, msk, 64);
        float p = ex / sm;

        if (lane < 32) pv[lane] = p;
        __syncthreads();

        // o[d] = sum_m p[m] * t[m][d]
        float po = 0.f;
        for (int mm = half * 16; mm < half * 16 + 16; mm++)
            po += pv[mm] * tb[mm * Dd + m];
        po += __shfl_xor(po, 32, 64);
        float newpre = item[m] + po;
        __syncthreads();
        if (lane < 32) pre[lane] = newpre;
        __syncthreads();

        // item[d] = sum_e pre[e] * W[d][e]
        float r = 0.f;
        for (int e = half * 16; e < half * 16 + 16; e++)
            r += pre[e] * W[m * Dd + e];
        r += __shfl_xor(r, 32, 64);
        __syncthreads();
        if (lane < 32) item[lane] = r;
        __syncthreads();
    }

    if (winner[pos] == b && lane < 32)
        out_i[(size_t)pos * Dd + lane] = item[lane];
}

// ---------------------------------------------------------------------------
extern "C" void kernel_launch(void* const* d_in, const int* in_sizes, int n_in,
                              void* d_out, int out_size, void* d_ws, size_t ws_size,
                              hipStream_t stream) {
    const int*   pos_items   = (const int*)d_in[0];
    const int*   memories_h  = (const int*)d_in[1];
    const int*   memories_r  = (const int*)d_in[2];
    const int*   memories_t  = (const int*)d_in[3];
    const float* uEmbed      = (const float*)d_in[4];
    const float* iEmbed      = (const float*)d_in[5];
    const float* entity_emb  = (const float*)d_in[6];
    const float* relation_emb= (const float*)d_in[7];
    const float* transform_W = (const float*)d_in[8];

    const int n_user_elems = in_sizes[4];   // USER*D = 3,200,000
    const int n_item_elems = in_sizes[5];   // ITEM*D = 3,200,000
    const int n_items      = n_item_elems / Dd;

    float* out_u = (float*)d_out;
    float* out_i = out_u + n_user_elems;
    float* out_h = out_i + n_item_elems;
    float* out_t = out_h + (size_t)NSLOT * Dd;
    float* out_r = out_t + (size_t)NSLOT * Dd;

    // workspace: winner[ITEM] ints, then Rh[NSLOT*D] floats
    int*   winner = (int*)d_ws;
    float* Rh     = (float*)((char*)d_ws + 512 * 1024);

    // init winner to -1
    (void)hipMemsetAsync(winner, 0xFF, (size_t)n_items * sizeof(int), stream);

    // passthrough copies
    {
        int n4 = n_user_elems / 4;
        int blocks = (n4 + 255) / 256;
        copy_ui_kernel<<<blocks, 256, 0, stream>>>(
            (const f32x4*)uEmbed, (const f32x4*)iEmbed,
            (f32x4*)out_u, (f32x4*)out_i, n4);
    }

    // last-wins winner map
    winner_kernel<<<(B + 255) / 256, 256, 0, stream>>>(pos_items, winner, B);

    // big gather + fused Rh
    {
        int waves_per_block = 4;                 // 256 threads
        int blocks = NSLOT / waves_per_block;    // 32768
        gather_kernel<<<blocks, 256, 0, stream>>>(
            memories_h, memories_r, memories_t, entity_emb, relation_emb,
            out_h, out_t, out_r, Rh);
    }

    // ripple hops + scatter
    ripple_kernel<<<B, 64, 0, stream>>>(pos_items, iEmbed, transform_W,
                                        Rh, out_t, winner, out_i);
}